// Round 9
// baseline (946.825 us; speedup 1.0000x reference)
//
#include <hip/hip_runtime.h>
#include <math.h>

#define NN 50000
#define NE 800000
#define EMB 128
#define HID 256
#define NF 7
#define EF 5
#define NL 5
#define BN_EPS 1e-5f
#define NREP 32     // stats replicas to kill same-line atomic serialization
#define SCAN_B 196  // ceil(NN/256)

typedef __attribute__((ext_vector_type(8))) short bf16x8;
typedef __attribute__((ext_vector_type(4))) float f32x4;

__device__ inline unsigned short f2b(float f) {  // fp32 -> bf16 RNE
    unsigned u = __builtin_bit_cast(unsigned, f);
    return (unsigned short)((u + 0x7fffu + ((u >> 16) & 1u)) >> 16);
}
__device__ inline float b2f(unsigned us) {
    return __builtin_bit_cast(float, us << 16);
}
// split x into hi+lo bf16 pair (packed as 2 cols per unsigned)
__device__ inline void split2(float a, float b, unsigned& hi, unsigned& lo) {
    unsigned short ha = f2b(a), hb = f2b(b);
    unsigned short la = f2b(a - b2f(ha)), lb = f2b(b - b2f(hb));
    hi = (unsigned)ha | ((unsigned)hb << 16);
    lo = (unsigned)la | ((unsigned)lb << 16);
}
// fp16 pack/unpack
__device__ inline unsigned pkh2(float a, float b) {
    union { unsigned v; _Float16 h[2]; } x;
    x.h[0] = (_Float16)a; x.h[1] = (_Float16)b;
    return x.v;
}
__device__ inline float2 uph2(unsigned u) {
    union { unsigned v; _Float16 h[2]; } x; x.v = u;
    return make_float2((float)x.h[0], (float)x.h[1]);
}

// ---------------------------------------------------------------------------
// k_prep: block 0 computes bias-sum vectors; all blocks zero CSR counts/cursor
// and the BN-stats replicas (fused agg+mlp can no longer zero them safely).
// ---------------------------------------------------------------------------
__global__ void k_prep(const float* __restrict__ b_x, const float* __restrict__ b_e,
                       float* __restrict__ bsum_x, float* __restrict__ bsum_e,
                       int* __restrict__ counts, int* __restrict__ cursor,
                       float* __restrict__ stats) {
    int tid = threadIdx.x;
    if (blockIdx.x == 0 && tid < EMB) {
        float s = 0.f;
        for (int f = 0; f < NF; ++f) s += b_x[f * EMB + tid];
        bsum_x[tid] = s;
        for (int l = 0; l < NL; ++l) {
            float se = 0.f;
            for (int f = 0; f < EF; ++f) se += b_e[(l * EF + f) * EMB + tid];
            bsum_e[l * EMB + tid] = se;
        }
    }
    int gid = blockIdx.x * blockDim.x + tid;
    int stride = gridDim.x * blockDim.x;
    for (int i = gid; i < NN; i += stride) { counts[i] = 0; cursor[i] = 0; }
    for (int i = gid; i < NREP * 2 * EMB; i += stride) stats[i] = 0.f;
}

// ---------------------------------------------------------------------------
// k_prepw: fragment-pack + hi/lo bf16 split of weights.
// W1p layout: [L][wave(4)][h2(4)][kk(4)][lane(64)][j(8)]  (lane-contiguous 16B)
// W2p layout: [L][wave(4)][o2(2)][kk(8)][lane(64)][j(8)]
// ---------------------------------------------------------------------------
__global__ void k_prepw(const float* __restrict__ W1, const float* __restrict__ W2,
                        unsigned short* __restrict__ W1ph, unsigned short* __restrict__ W1pl,
                        unsigned short* __restrict__ W2ph, unsigned short* __restrict__ W2pl) {
    const int TOT = NL * EMB * HID;   // 163840 per matrix
    int gid = blockIdx.x * blockDim.x + threadIdx.x;
    if (gid < TOT) {
        int l = gid / (EMB * HID);
        int r = gid % (EMB * HID);             // 32768
        int w = r >> 13;                       // /8192
        int rem = r & 8191;
        int h2 = rem >> 11;                    // /2048
        int rem2 = rem & 2047;
        int kk = rem2 >> 9;                    // /512
        int rem3 = rem2 & 511;
        int lane = rem3 >> 3;
        int j = rem3 & 7;
        int hc = w * 64 + h2 * 16 + (lane & 15);
        int k = kk * 32 + (lane >> 4) * 8 + j;
        float wv = W1[((size_t)l * EMB + k) * HID + hc];
        unsigned short hi = f2b(wv);
        W1ph[gid] = hi;
        W1pl[gid] = f2b(wv - b2f(hi));
    } else if (gid < 2 * TOT) {
        int g = gid - TOT;
        int l = g / (EMB * HID);
        int r = g % (EMB * HID);
        int w = r >> 13;
        int rem = r & 8191;
        int o2 = rem >> 12;                    // /4096
        int rem2 = rem & 4095;
        int kk = rem2 >> 9;
        int rem3 = rem2 & 511;
        int lane = rem3 >> 3;
        int j = rem3 & 7;
        int oc = w * 32 + o2 * 16 + (lane & 15);
        int k2 = kk * 32 + (lane >> 4) * 8 + j;
        float wv = W2[((size_t)l * HID + k2) * EMB + oc];
        unsigned short hi = f2b(wv);
        W2ph[g] = hi;
        W2pl[g] = f2b(wv - b2f(hi));
    }
}

// ---------------------------------------------------------------------------
// k_init: h(fp16) = x @ W_x + bsum_x  (32 threads/node, 4 cols each)
// ---------------------------------------------------------------------------
__global__ void k_init(const float* __restrict__ x, const float* __restrict__ W_x,
                       const float* __restrict__ bsum_x, unsigned short* __restrict__ h16) {
    int gid = blockIdx.x * blockDim.x + threadIdx.x;
    int v = gid >> 5;
    if (v >= NN) return;
    int c = (gid & 31) << 2;
    float4 acc = *(const float4*)(bsum_x + c);
    #pragma unroll
    for (int f = 0; f < NF; ++f) {
        float xv = x[(size_t)v * NF + f];
        float4 w = *(const float4*)(W_x + f * EMB + c);
        acc.x += xv * w.x; acc.y += xv * w.y; acc.z += xv * w.z; acc.w += xv * w.w;
    }
    uint2 p = make_uint2(pkh2(acc.x, acc.y), pkh2(acc.z, acc.w));
    *(uint2*)(h16 + (size_t)v * EMB + c) = p;
}

// ---------------------------------------------------------------------------
// CSR build: histogram of dst, 3-phase multi-block scan, packed bucket fill
// ---------------------------------------------------------------------------
__global__ void k_hist(const int* __restrict__ dst, int* __restrict__ counts) {
    int e = blockIdx.x * blockDim.x + threadIdx.x;
    if (e < NE) atomicAdd(&counts[dst[e]], 1);
}

__global__ void k_scan1(const int* __restrict__ counts, int* __restrict__ bsum) {
    int tid = threadIdx.x;
    int i = blockIdx.x * 256 + tid;
    int v = (i < NN) ? counts[i] : 0;
    #pragma unroll
    for (int off = 1; off < 64; off <<= 1) v += __shfl_xor(v, off, 64);
    __shared__ int ws[4];
    if ((tid & 63) == 0) ws[tid >> 6] = v;
    __syncthreads();
    if (tid == 0) bsum[blockIdx.x] = ws[0] + ws[1] + ws[2] + ws[3];
}

__global__ void k_scan2(const int* __restrict__ bsum, int* __restrict__ bpre,
                        int* __restrict__ row_start) {
    int tid = threadIdx.x;  // 256 threads
    int x = (tid < SCAN_B) ? bsum[tid] : 0;
    int lane = tid & 63, wv = tid >> 6;
    int v = x;
    #pragma unroll
    for (int off = 1; off < 64; off <<= 1) {
        int t = __shfl_up(v, off, 64);
        if (lane >= off) v += t;
    }
    __shared__ int wsum[4];
    if (lane == 63) wsum[wv] = v;
    __syncthreads();
    int woff = 0;
    #pragma unroll
    for (int w = 0; w < 4; ++w) if (w < wv) woff += wsum[w];
    int incl = v + woff;
    if (tid < SCAN_B) bpre[tid] = incl - x;
    if (tid == 255) row_start[NN] = incl;
}

__global__ void k_scan3(const int* __restrict__ counts, const int* __restrict__ bpre,
                        int* __restrict__ row_start) {
    int tid = threadIdx.x;
    int i = blockIdx.x * 256 + tid;
    int x = (i < NN) ? counts[i] : 0;
    int lane = tid & 63, wv = tid >> 6;
    int v = x;
    #pragma unroll
    for (int off = 1; off < 64; off <<= 1) {
        int t = __shfl_up(v, off, 64);
        if (lane >= off) v += t;
    }
    __shared__ int wsum[4];
    if (lane == 63) wsum[wv] = v;
    __syncthreads();
    int woff = 0;
    #pragma unroll
    for (int w = 0; w < 4; ++w) if (w < wv) woff += wsum[w];
    if (i < NN) row_start[i] = bpre[blockIdx.x] + v + woff - x;
}

// k_fill: ONE 16-B scatter per edge: {src, fp16 ea0..ea4}.
__global__ void k_fill(const int* __restrict__ src, const int* __restrict__ dst,
                       const float* __restrict__ edge_attr,
                       const int* __restrict__ row_start, int* __restrict__ cursor,
                       uint4* __restrict__ sorted_pk) {
    int e = blockIdx.x * blockDim.x + threadIdx.x;
    if (e >= NE) return;
    int d = dst[e];
    int pos = atomicAdd(&cursor[d], 1);
    int idx = row_start[d] + pos;
    const float* ea = edge_attr + (size_t)e * EF;
    float a0 = ea[0], a1 = ea[1], a2 = ea[2], a3 = ea[3], a4 = ea[4];
    uint4 pk;
    pk.x = (unsigned)src[e];
    pk.y = pkh2(a0, a1);
    pk.z = pkh2(a2, a3);
    pk.w = pkh2(a4, 0.f);
    sorted_pk[idx] = pk;
}

// ---------------------------------------------------------------------------
// k_esum (once): per node, sum incoming edge attrs -> attsum[v][8] =
// {a0..a4, deg, 0, 0}; emit compact sorted_srcc[e] (sequential write).
// ---------------------------------------------------------------------------
__global__ void k_esum(const uint4* __restrict__ sorted_pk,
                       const int* __restrict__ row_start,
                       float* __restrict__ attsum, int* __restrict__ sorted_srcc) {
    int v = blockIdx.x * blockDim.x + threadIdx.x;
    if (v >= NN) return;
    int e0 = row_start[v], e1 = row_start[v + 1];
    float s0 = 0.f, s1 = 0.f, s2 = 0.f, s3 = 0.f, s4 = 0.f;
    for (int e = e0; e < e1; ++e) {
        uint4 pk = sorted_pk[e];
        sorted_srcc[e] = (int)pk.x;
        float2 a01 = uph2(pk.y), a23 = uph2(pk.z), a4x = uph2(pk.w);
        s0 += a01.x; s1 += a01.y; s2 += a23.x; s3 += a23.y; s4 += a4x.x;
    }
    float* o = attsum + (size_t)v * 8;
    *(float4*)(o) = make_float4(s0, s1, s2, s3);
    *(float4*)(o + 4) = make_float4(s4, (float)(e1 - e0), 0.f, 0.f);
}

// ---------------------------------------------------------------------------
// k_aggmlp (FUSED): per 32-node tile, gather+aggregate straight into the LDS
// A-tile (split hi/lo bf16), then the two MFMA phases. Eliminates the
// agg_hi/agg_lo global round-trip (~38 MB/layer) and one launch per layer.
// Gather: wave w handles 8 nodes sequentially; lane owns cols 2*lane,2*lane+1;
// unroll-8 keeps 8 gathers in flight per wave (occupancy is LDS-capped at
// ~3 blocks/CU, less than standalone k_agg had).
// ---------------------------------------------------------------------------
__global__ __launch_bounds__(256) void k_aggmlp(
        const unsigned short* __restrict__ h16, const int* __restrict__ sorted_srcc,
        const float* __restrict__ attsum,
        const float* __restrict__ W_e_l, const float* __restrict__ bsum_e_l,
        const int* __restrict__ row_start,
        const unsigned short* __restrict__ W1ph, const unsigned short* __restrict__ W1pl,
        const float* __restrict__ b1_l,
        const unsigned short* __restrict__ W2ph, const unsigned short* __restrict__ W2pl,
        const float* __restrict__ b2_l,
        unsigned short* __restrict__ z16, float* __restrict__ stats) {
    __shared__ unsigned short Ahi[32][136];   // 8.5 KB  (+8 pad)
    __shared__ unsigned short Alo[32][136];   // 8.5 KB
    __shared__ unsigned short Hhi[32][264];   // 16.5 KB (+8 pad)
    __shared__ unsigned short Hlo[32][264];   // 16.5 KB
    int tid = threadIdx.x;
    int r0 = blockIdx.x * 32;
    int rep = blockIdx.x & (NREP - 1);
    int wave = tid >> 6, lane = tid & 63;
    int l16 = lane & 15, quad = lane >> 4;
    // ---- gather/aggregate phase: wave w -> nodes r0+w*8 .. +7
    {
        int c = lane << 1;
        float2 we0 = *(const float2*)(W_e_l + 0 * EMB + c);
        float2 we1 = *(const float2*)(W_e_l + 1 * EMB + c);
        float2 we2 = *(const float2*)(W_e_l + 2 * EMB + c);
        float2 we3 = *(const float2*)(W_e_l + 3 * EMB + c);
        float2 we4 = *(const float2*)(W_e_l + 4 * EMB + c);
        float2 bs = *(const float2*)(bsum_e_l + c);
        #pragma unroll
        for (int i = 0; i < 8; ++i) {
            int n = wave * 8 + i;
            int v = r0 + n;
            unsigned phi = 0u, plo = 0u;
            if (v < NN) {
                float2 hv = uph2(*(const unsigned*)(h16 + (size_t)v * EMB + c));
                const float* at = attsum + (size_t)v * 8;
                float4 a03 = *(const float4*)(at);
                float2 a45 = *(const float2*)(at + 4);   // a4, deg
                float ax = hv.x + (a45.y + 1.f) * bs.x
                         + a03.x*we0.x + a03.y*we1.x + a03.z*we2.x + a03.w*we3.x + a45.x*we4.x;
                float ay = hv.y + (a45.y + 1.f) * bs.y
                         + a03.x*we0.y + a03.y*we1.y + a03.z*we2.y + a03.w*we3.y + a45.x*we4.y;
                int e0 = row_start[v], e1 = row_start[v + 1];
                int e = e0;
                for (; e + 8 <= e1; e += 8) {
                    int s0 = __builtin_amdgcn_readfirstlane(sorted_srcc[e + 0]);
                    int s1 = __builtin_amdgcn_readfirstlane(sorted_srcc[e + 1]);
                    int s2 = __builtin_amdgcn_readfirstlane(sorted_srcc[e + 2]);
                    int s3 = __builtin_amdgcn_readfirstlane(sorted_srcc[e + 3]);
                    int s4 = __builtin_amdgcn_readfirstlane(sorted_srcc[e + 4]);
                    int s5 = __builtin_amdgcn_readfirstlane(sorted_srcc[e + 5]);
                    int s6 = __builtin_amdgcn_readfirstlane(sorted_srcc[e + 6]);
                    int s7 = __builtin_amdgcn_readfirstlane(sorted_srcc[e + 7]);
                    unsigned u0 = *(const unsigned*)(h16 + (size_t)s0 * EMB + c);
                    unsigned u1 = *(const unsigned*)(h16 + (size_t)s1 * EMB + c);
                    unsigned u2 = *(const unsigned*)(h16 + (size_t)s2 * EMB + c);
                    unsigned u3 = *(const unsigned*)(h16 + (size_t)s3 * EMB + c);
                    unsigned u4 = *(const unsigned*)(h16 + (size_t)s4 * EMB + c);
                    unsigned u5 = *(const unsigned*)(h16 + (size_t)s5 * EMB + c);
                    unsigned u6 = *(const unsigned*)(h16 + (size_t)s6 * EMB + c);
                    unsigned u7 = *(const unsigned*)(h16 + (size_t)s7 * EMB + c);
                    float2 h0 = uph2(u0), h1 = uph2(u1), h2 = uph2(u2), h3 = uph2(u3);
                    float2 h4 = uph2(u4), h5 = uph2(u5), h6 = uph2(u6), h7 = uph2(u7);
                    ax += ((h0.x + h1.x) + (h2.x + h3.x)) + ((h4.x + h5.x) + (h6.x + h7.x));
                    ay += ((h0.y + h1.y) + (h2.y + h3.y)) + ((h4.y + h5.y) + (h6.y + h7.y));
                }
                for (; e < e1; ++e) {
                    int s = __builtin_amdgcn_readfirstlane(sorted_srcc[e]);
                    float2 hs = uph2(*(const unsigned*)(h16 + (size_t)s * EMB + c));
                    ax += hs.x;
                    ay += hs.y;
                }
                split2(ax, ay, phi, plo);
            }
            *(unsigned*)(&Ahi[n][c]) = phi;
            *(unsigned*)(&Alo[n][c]) = plo;
        }
    }
    __syncthreads();
    // ---- MFMA phase 1: wave owns hid cols [64*wave, 64*wave+64)
    {
        bf16x8 ahi[2][4], alo[2][4];
        #pragma unroll
        for (int nt = 0; nt < 2; ++nt)
            #pragma unroll
            for (int kk = 0; kk < 4; ++kk) {
                ahi[nt][kk] = *(const bf16x8*)(&Ahi[nt * 16 + l16][kk * 32 + quad * 8]);
                alo[nt][kk] = *(const bf16x8*)(&Alo[nt * 16 + l16][kk * 32 + quad * 8]);
            }
        #pragma unroll
        for (int h2 = 0; h2 < 4; ++h2) {
            bf16x8 whi[4], wlo[4];
            #pragma unroll
            for (int kk = 0; kk < 4; ++kk) {
                size_t off = ((((size_t)(wave * 4 + h2) * 4) + kk) * 64 + lane) * 8;
                whi[kk] = *(const bf16x8*)(W1ph + off);
                wlo[kk] = *(const bf16x8*)(W1pl + off);
            }
            float4 bv = *(const float4*)(b1_l + wave * 64 + h2 * 16 + quad * 4);
            f32x4 bias = {bv.x, bv.y, bv.z, bv.w};
            #pragma unroll
            for (int nt = 0; nt < 2; ++nt) {
                f32x4 acc = bias;
                #pragma unroll
                for (int kk = 0; kk < 4; ++kk)
                    acc = __builtin_amdgcn_mfma_f32_16x16x32_bf16(whi[kk], ahi[nt][kk], acc, 0, 0, 0);
                #pragma unroll
                for (int kk = 0; kk < 4; ++kk)
                    acc = __builtin_amdgcn_mfma_f32_16x16x32_bf16(whi[kk], alo[nt][kk], acc, 0, 0, 0);
                #pragma unroll
                for (int kk = 0; kk < 4; ++kk)
                    acc = __builtin_amdgcn_mfma_f32_16x16x32_bf16(wlo[kk], ahi[nt][kk], acc, 0, 0, 0);
                float v0 = fmaxf(acc[0], 0.f), v1 = fmaxf(acc[1], 0.f);
                float v2 = fmaxf(acc[2], 0.f), v3 = fmaxf(acc[3], 0.f);
                unsigned hiA, loA, hiB, loB;
                split2(v0, v1, hiA, loA);
                split2(v2, v3, hiB, loB);
                int col = wave * 64 + h2 * 16 + quad * 4;
                *(uint2*)(&Hhi[nt * 16 + l16][col]) = make_uint2(hiA, hiB);
                *(uint2*)(&Hlo[nt * 16 + l16][col]) = make_uint2(loA, loB);
            }
        }
    }
    __syncthreads();
    // ---- MFMA phase 2: wave owns out cols [32*wave, 32*wave+32)
    float ss[2][4] = {}, sq[2][4] = {};
    #pragma unroll
    for (int o2 = 0; o2 < 2; ++o2) {
        bf16x8 w2h[8], w2l[8];
        #pragma unroll
        for (int kk = 0; kk < 8; ++kk) {
            size_t off = ((((size_t)(wave * 2 + o2) * 8) + kk) * 64 + lane) * 8;
            w2h[kk] = *(const bf16x8*)(W2ph + off);
            w2l[kk] = *(const bf16x8*)(W2pl + off);
        }
        float4 bv = *(const float4*)(b2_l + wave * 32 + o2 * 16 + quad * 4);
        f32x4 bias = {bv.x, bv.y, bv.z, bv.w};
        #pragma unroll
        for (int nt = 0; nt < 2; ++nt) {
            bf16x8 hh[8], hl[8];
            #pragma unroll
            for (int kk = 0; kk < 8; ++kk) {
                hh[kk] = *(const bf16x8*)(&Hhi[nt * 16 + l16][kk * 32 + quad * 8]);
                hl[kk] = *(const bf16x8*)(&Hlo[nt * 16 + l16][kk * 32 + quad * 8]);
            }
            f32x4 acc = bias;
            #pragma unroll
            for (int kk = 0; kk < 8; ++kk)
                acc = __builtin_amdgcn_mfma_f32_16x16x32_bf16(w2h[kk], hh[kk], acc, 0, 0, 0);
            #pragma unroll
            for (int kk = 0; kk < 8; ++kk)
                acc = __builtin_amdgcn_mfma_f32_16x16x32_bf16(w2h[kk], hl[kk], acc, 0, 0, 0);
            #pragma unroll
            for (int kk = 0; kk < 8; ++kk)
                acc = __builtin_amdgcn_mfma_f32_16x16x32_bf16(w2l[kk], hh[kk], acc, 0, 0, 0);
            int node = r0 + nt * 16 + l16;
            if (node < NN) {
                uint2 p = make_uint2(pkh2(acc[0], acc[1]), pkh2(acc[2], acc[3]));
                *(uint2*)(z16 + (size_t)node * EMB + wave * 32 + o2 * 16 + quad * 4) = p;
                #pragma unroll
                for (int r = 0; r < 4; ++r) {
                    ss[o2][r] += acc[r];
                    sq[o2][r] += acc[r] * acc[r];
                }
            }
        }
    }
    #pragma unroll
    for (int o2 = 0; o2 < 2; ++o2)
        #pragma unroll
        for (int r = 0; r < 4; ++r) {
            float s = ss[o2][r], q = sq[o2][r];
            #pragma unroll
            for (int m = 1; m < 16; m <<= 1) {
                s += __shfl_xor(s, m, 64);
                q += __shfl_xor(q, m, 64);
            }
            if (l16 == 0) {
                int oc = wave * 32 + o2 * 16 + quad * 4 + r;
                atomicAdd(&stats[rep * 2 * EMB + oc], s);
                atomicAdd(&stats[rep * 2 * EMB + EMB + oc], q);
            }
        }
}

// ---------------------------------------------------------------------------
// k_bnscale: ONE block reduces the NREP stats replicas -> sc/sh (1 KB),
// then re-zeroes the replicas for the next layer (barrier between read+zero).
// ---------------------------------------------------------------------------
__global__ void k_bnscale(float* __restrict__ stats,
                          const float* __restrict__ gamma_l, const float* __restrict__ beta_l,
                          float* __restrict__ scsh) {
    int tid = threadIdx.x;  // 128 threads
    float s = 0.f, q = 0.f;
    #pragma unroll
    for (int r = 0; r < NREP; ++r) {
        s += stats[r * 2 * EMB + tid];
        q += stats[r * 2 * EMB + EMB + tid];
    }
    __syncthreads();   // all reads done before anyone zeroes
    for (int i = tid; i < NREP * 2 * EMB; i += 128) stats[i] = 0.f;
    float mu = s * (1.f / NN);
    float var = q * (1.f / NN) - mu * mu;
    float sf = gamma_l[tid] * rsqrtf(var + BN_EPS);
    scsh[tid] = sf;
    scsh[EMB + tid] = beta_l[tid] - mu * sf;
}

// ---------------------------------------------------------------------------
// k_bn: z16 -> z*sc + sh; ELU -> fp16 h except last layer (fp32 to d_out).
// ---------------------------------------------------------------------------
__global__ void k_bn(const unsigned short* __restrict__ z16, const float* __restrict__ scsh,
                     unsigned short* __restrict__ h16, float* __restrict__ fout, int last) {
    __shared__ float sc[EMB], sh[EMB];
    int tid = threadIdx.x;
    if (tid < EMB) {
        sc[tid] = scsh[tid];
        sh[tid] = scsh[EMB + tid];
    }
    __syncthreads();
    int gid = blockIdx.x * blockDim.x + tid;
    if (gid >= NN * EMB / 4) return;
    int c = (gid & 31) << 2;
    uint2 zp = *(const uint2*)(z16 + (size_t)gid * 4);
    float2 z01 = uph2(zp.x), z23 = uph2(zp.y);
    float o0 = z01.x * sc[c + 0] + sh[c + 0];
    float o1 = z01.y * sc[c + 1] + sh[c + 1];
    float o2 = z23.x * sc[c + 2] + sh[c + 2];
    float o3 = z23.y * sc[c + 3] + sh[c + 3];
    if (!last) {
        o0 = (o0 > 0.f) ? o0 : (expf(o0) - 1.f);
        o1 = (o1 > 0.f) ? o1 : (expf(o1) - 1.f);
        o2 = (o2 > 0.f) ? o2 : (expf(o2) - 1.f);
        o3 = (o3 > 0.f) ? o3 : (expf(o3) - 1.f);
        uint2 p = make_uint2(pkh2(o0, o1), pkh2(o2, o3));
        *(uint2*)(h16 + (size_t)gid * 4) = p;
    } else {
        *(float4*)(fout + (size_t)gid * 4) = make_float4(o0, o1, o2, o3);
    }
}

// ---------------------------------------------------------------------------
extern "C" void kernel_launch(void* const* d_in, const int* in_sizes, int n_in,
                              void* d_out, int out_size, void* d_ws, size_t ws_size,
                              hipStream_t stream) {
    const float* x         = (const float*)d_in[0];
    const float* edge_attr = (const float*)d_in[1];
    const int*   edge_idx  = (const int*)d_in[2];
    const float* W_x   = (const float*)d_in[3];
    const float* b_x   = (const float*)d_in[4];
    const float* W_e   = (const float*)d_in[5];
    const float* b_e   = (const float*)d_in[6];
    const float* W1    = (const float*)d_in[7];
    const float* b1    = (const float*)d_in[8];
    const float* W2    = (const float*)d_in[9];
    const float* b2    = (const float*)d_in[10];
    const float* gamma = (const float*)d_in[11];
    const float* beta  = (const float*)d_in[12];
    float* fout = (float*)d_out;  // final BN writes fp32 here

    const int* src = edge_idx;
    const int* dst = edge_idx + NE;

    char* p = (char*)d_ws;
    auto alloc = [&](size_t bytes) { char* q = p; p += (bytes + 255) & ~(size_t)255; return q; };
    unsigned short* h16 = (unsigned short*)alloc((size_t)NN * EMB * 2);
    unsigned short* z16 = (unsigned short*)alloc((size_t)NN * EMB * 2);
    unsigned short* W1ph = (unsigned short*)alloc((size_t)NL * HID * EMB * 2);
    unsigned short* W1pl = (unsigned short*)alloc((size_t)NL * HID * EMB * 2);
    unsigned short* W2ph = (unsigned short*)alloc((size_t)NL * EMB * HID * 2);
    unsigned short* W2pl = (unsigned short*)alloc((size_t)NL * EMB * HID * 2);
    int*   row_start  = (int*)alloc((NN + 1) * sizeof(int));
    int*   counts     = (int*)alloc(NN * sizeof(int));
    int*   cursor     = (int*)alloc(NN * sizeof(int));
    uint4* sorted_pk  = (uint4*)alloc((size_t)NE * sizeof(uint4));
    int*   sorted_srcc= (int*)alloc((size_t)NE * sizeof(int));
    float* attsum     = (float*)alloc((size_t)NN * 8 * sizeof(float));
    int*   bsum       = (int*)alloc(SCAN_B * sizeof(int));
    int*   bpre       = (int*)alloc(SCAN_B * sizeof(int));
    float* stats      = (float*)alloc((size_t)NREP * 2 * EMB * sizeof(float));
    float* scsh       = (float*)alloc(2 * EMB * sizeof(float));
    float* bsum_x     = (float*)alloc(EMB * sizeof(float));
    float* bsum_e     = (float*)alloc(NL * EMB * sizeof(float));

    k_prep<<<256, 256, 0, stream>>>(b_x, b_e, bsum_x, bsum_e, counts, cursor, stats);
    k_prepw<<<(2 * NL * EMB * HID + 255) / 256, 256, 0, stream>>>(W1, W2, W1ph, W1pl, W2ph, W2pl);
    k_init<<<(NN * 32 + 255) / 256, 256, 0, stream>>>(x, W_x, bsum_x, h16);
    k_hist<<<(NE + 255) / 256, 256, 0, stream>>>(dst, counts);
    k_scan1<<<SCAN_B, 256, 0, stream>>>(counts, bsum);
    k_scan2<<<1, 256, 0, stream>>>(bsum, bpre, row_start);
    k_scan3<<<SCAN_B, 256, 0, stream>>>(counts, bpre, row_start);
    k_fill<<<(NE + 255) / 256, 256, 0, stream>>>(src, dst, edge_attr, row_start, cursor,
                                                 sorted_pk);
    k_esum<<<SCAN_B, 256, 0, stream>>>(sorted_pk, row_start, attsum, sorted_srcc);
    for (int l = 0; l < NL; ++l) {
        k_aggmlp<<<(NN + 31) / 32, 256, 0, stream>>>(
            h16, sorted_srcc, attsum, W_e + (size_t)l * EF * EMB, bsum_e + l * EMB,
            row_start,
            W1ph + (size_t)l * HID * EMB, W1pl + (size_t)l * HID * EMB, b1 + (size_t)l * HID,
            W2ph + (size_t)l * EMB * HID, W2pl + (size_t)l * EMB * HID, b2 + (size_t)l * EMB,
            z16, stats);
        k_bnscale<<<1, 128, 0, stream>>>(stats, gamma + l * EMB, beta + l * EMB, scsh);
        k_bn<<<(NN * EMB / 4 + 255) / 256, 256, 0, stream>>>(
            z16, scsh, h16, fout, (l == NL - 1) ? 1 : 0);
    }
}

// Round 10
// 634.611 us; speedup vs baseline: 1.4920x; 1.4920x over previous
//
#include <hip/hip_runtime.h>
#include <math.h>

#define NN 50000
#define NE 800000
#define EMB 128
#define HID 256
#define NF 7
#define EF 5
#define NL 5
#define BN_EPS 1e-5f
#define NREP 32     // stats replicas to kill same-line atomic serialization
#define SCAN_B 196  // ceil(NN/256)

typedef __attribute__((ext_vector_type(8))) short bf16x8;
typedef __attribute__((ext_vector_type(4))) float f32x4;

__device__ inline unsigned short f2b(float f) {  // fp32 -> bf16 RNE
    unsigned u = __builtin_bit_cast(unsigned, f);
    return (unsigned short)((u + 0x7fffu + ((u >> 16) & 1u)) >> 16);
}
__device__ inline float b2f(unsigned us) {
    return __builtin_bit_cast(float, us << 16);
}
// split x into hi+lo bf16 pair (packed as 2 cols per unsigned)
__device__ inline void split2(float a, float b, unsigned& hi, unsigned& lo) {
    unsigned short ha = f2b(a), hb = f2b(b);
    unsigned short la = f2b(a - b2f(ha)), lb = f2b(b - b2f(hb));
    hi = (unsigned)ha | ((unsigned)hb << 16);
    lo = (unsigned)la | ((unsigned)lb << 16);
}
// fp16 pack/unpack
__device__ inline unsigned pkh2(float a, float b) {
    union { unsigned v; _Float16 h[2]; } x;
    x.h[0] = (_Float16)a; x.h[1] = (_Float16)b;
    return x.v;
}
__device__ inline float2 uph2(unsigned u) {
    union { unsigned v; _Float16 h[2]; } x; x.v = u;
    return make_float2((float)x.h[0], (float)x.h[1]);
}

// ---------------------------------------------------------------------------
// k_prep: block 0 computes bias-sum vectors; all blocks zero CSR counts/cursor
// ---------------------------------------------------------------------------
__global__ void k_prep(const float* __restrict__ b_x, const float* __restrict__ b_e,
                       float* __restrict__ bsum_x, float* __restrict__ bsum_e,
                       int* __restrict__ counts, int* __restrict__ cursor) {
    int tid = threadIdx.x;
    if (blockIdx.x == 0 && tid < EMB) {
        float s = 0.f;
        for (int f = 0; f < NF; ++f) s += b_x[f * EMB + tid];
        bsum_x[tid] = s;
        for (int l = 0; l < NL; ++l) {
            float se = 0.f;
            for (int f = 0; f < EF; ++f) se += b_e[(l * EF + f) * EMB + tid];
            bsum_e[l * EMB + tid] = se;
        }
    }
    int gid = blockIdx.x * blockDim.x + tid;
    int stride = gridDim.x * blockDim.x;
    for (int i = gid; i < NN; i += stride) { counts[i] = 0; cursor[i] = 0; }
}

// ---------------------------------------------------------------------------
// k_prepw: fragment-pack + hi/lo bf16 split of weights.
// W1p layout: [L][wave(4)][h2(4)][kk(4)][lane(64)][j(8)]  (lane-contiguous 16B)
// W2p layout: [L][wave(4)][o2(2)][kk(8)][lane(64)][j(8)]
// ---------------------------------------------------------------------------
__global__ void k_prepw(const float* __restrict__ W1, const float* __restrict__ W2,
                        unsigned short* __restrict__ W1ph, unsigned short* __restrict__ W1pl,
                        unsigned short* __restrict__ W2ph, unsigned short* __restrict__ W2pl) {
    const int TOT = NL * EMB * HID;   // 163840 per matrix
    int gid = blockIdx.x * blockDim.x + threadIdx.x;
    if (gid < TOT) {
        int l = gid / (EMB * HID);
        int r = gid % (EMB * HID);             // 32768
        int w = r >> 13;                       // /8192
        int rem = r & 8191;
        int h2 = rem >> 11;                    // /2048
        int rem2 = rem & 2047;
        int kk = rem2 >> 9;                    // /512
        int rem3 = rem2 & 511;
        int lane = rem3 >> 3;
        int j = rem3 & 7;
        int hc = w * 64 + h2 * 16 + (lane & 15);
        int k = kk * 32 + (lane >> 4) * 8 + j;
        float wv = W1[((size_t)l * EMB + k) * HID + hc];
        unsigned short hi = f2b(wv);
        W1ph[gid] = hi;
        W1pl[gid] = f2b(wv - b2f(hi));
    } else if (gid < 2 * TOT) {
        int g = gid - TOT;
        int l = g / (EMB * HID);
        int r = g % (EMB * HID);
        int w = r >> 13;
        int rem = r & 8191;
        int o2 = rem >> 12;                    // /4096
        int rem2 = rem & 4095;
        int kk = rem2 >> 9;
        int rem3 = rem2 & 511;
        int lane = rem3 >> 3;
        int j = rem3 & 7;
        int oc = w * 32 + o2 * 16 + (lane & 15);
        int k2 = kk * 32 + (lane >> 4) * 8 + j;
        float wv = W2[((size_t)l * HID + k2) * EMB + oc];
        unsigned short hi = f2b(wv);
        W2ph[g] = hi;
        W2pl[g] = f2b(wv - b2f(hi));
    }
}

// ---------------------------------------------------------------------------
// k_init: h(fp16) = x @ W_x + bsum_x  (32 threads/node, 4 cols each)
// ---------------------------------------------------------------------------
__global__ void k_init(const float* __restrict__ x, const float* __restrict__ W_x,
                       const float* __restrict__ bsum_x, unsigned short* __restrict__ h16) {
    int gid = blockIdx.x * blockDim.x + threadIdx.x;
    int v = gid >> 5;
    if (v >= NN) return;
    int c = (gid & 31) << 2;
    float4 acc = *(const float4*)(bsum_x + c);
    #pragma unroll
    for (int f = 0; f < NF; ++f) {
        float xv = x[(size_t)v * NF + f];
        float4 w = *(const float4*)(W_x + f * EMB + c);
        acc.x += xv * w.x; acc.y += xv * w.y; acc.z += xv * w.z; acc.w += xv * w.w;
    }
    uint2 p = make_uint2(pkh2(acc.x, acc.y), pkh2(acc.z, acc.w));
    *(uint2*)(h16 + (size_t)v * EMB + c) = p;
}

// ---------------------------------------------------------------------------
// CSR build: histogram of dst, 3-phase multi-block scan, packed bucket fill
// ---------------------------------------------------------------------------
__global__ void k_hist(const int* __restrict__ dst, int* __restrict__ counts) {
    int e = blockIdx.x * blockDim.x + threadIdx.x;
    if (e < NE) atomicAdd(&counts[dst[e]], 1);
}

__global__ void k_scan1(const int* __restrict__ counts, int* __restrict__ bsum) {
    int tid = threadIdx.x;
    int i = blockIdx.x * 256 + tid;
    int v = (i < NN) ? counts[i] : 0;
    #pragma unroll
    for (int off = 1; off < 64; off <<= 1) v += __shfl_xor(v, off, 64);
    __shared__ int ws[4];
    if ((tid & 63) == 0) ws[tid >> 6] = v;
    __syncthreads();
    if (tid == 0) bsum[blockIdx.x] = ws[0] + ws[1] + ws[2] + ws[3];
}

__global__ void k_scan2(const int* __restrict__ bsum, int* __restrict__ bpre,
                        int* __restrict__ row_start) {
    int tid = threadIdx.x;  // 256 threads
    int x = (tid < SCAN_B) ? bsum[tid] : 0;
    int lane = tid & 63, wv = tid >> 6;
    int v = x;
    #pragma unroll
    for (int off = 1; off < 64; off <<= 1) {
        int t = __shfl_up(v, off, 64);
        if (lane >= off) v += t;
    }
    __shared__ int wsum[4];
    if (lane == 63) wsum[wv] = v;
    __syncthreads();
    int woff = 0;
    #pragma unroll
    for (int w = 0; w < 4; ++w) if (w < wv) woff += wsum[w];
    int incl = v + woff;
    if (tid < SCAN_B) bpre[tid] = incl - x;
    if (tid == 255) row_start[NN] = incl;
}

__global__ void k_scan3(const int* __restrict__ counts, const int* __restrict__ bpre,
                        int* __restrict__ row_start) {
    int tid = threadIdx.x;
    int i = blockIdx.x * 256 + tid;
    int x = (i < NN) ? counts[i] : 0;
    int lane = tid & 63, wv = tid >> 6;
    int v = x;
    #pragma unroll
    for (int off = 1; off < 64; off <<= 1) {
        int t = __shfl_up(v, off, 64);
        if (lane >= off) v += t;
    }
    __shared__ int wsum[4];
    if (lane == 63) wsum[wv] = v;
    __syncthreads();
    int woff = 0;
    #pragma unroll
    for (int w = 0; w < 4; ++w) if (w < wv) woff += wsum[w];
    if (i < NN) row_start[i] = bpre[blockIdx.x] + v + woff - x;
}

// k_fill: ONE 16-B scatter per edge: {src, fp16 ea0..ea4}.
__global__ void k_fill(const int* __restrict__ src, const int* __restrict__ dst,
                       const float* __restrict__ edge_attr,
                       const int* __restrict__ row_start, int* __restrict__ cursor,
                       uint4* __restrict__ sorted_pk) {
    int e = blockIdx.x * blockDim.x + threadIdx.x;
    if (e >= NE) return;
    int d = dst[e];
    int pos = atomicAdd(&cursor[d], 1);
    int idx = row_start[d] + pos;
    const float* ea = edge_attr + (size_t)e * EF;
    float a0 = ea[0], a1 = ea[1], a2 = ea[2], a3 = ea[3], a4 = ea[4];
    uint4 pk;
    pk.x = (unsigned)src[e];
    pk.y = pkh2(a0, a1);
    pk.z = pkh2(a2, a3);
    pk.w = pkh2(a4, 0.f);
    sorted_pk[idx] = pk;
}

// ---------------------------------------------------------------------------
// k_esum (once): per node, sum incoming edge attrs -> attsum[v][8] =
// {a0..a4, deg, 0, 0}; emit compact sorted_srcc[e] (sequential write).
// ---------------------------------------------------------------------------
__global__ void k_esum(const uint4* __restrict__ sorted_pk,
                       const int* __restrict__ row_start,
                       float* __restrict__ attsum, int* __restrict__ sorted_srcc) {
    int v = blockIdx.x * blockDim.x + threadIdx.x;
    if (v >= NN) return;
    int e0 = row_start[v], e1 = row_start[v + 1];
    float s0 = 0.f, s1 = 0.f, s2 = 0.f, s3 = 0.f, s4 = 0.f;
    for (int e = e0; e < e1; ++e) {
        uint4 pk = sorted_pk[e];
        sorted_srcc[e] = (int)pk.x;
        float2 a01 = uph2(pk.y), a23 = uph2(pk.z), a4x = uph2(pk.w);
        s0 += a01.x; s1 += a01.y; s2 += a23.x; s3 += a23.y; s4 += a4x.x;
    }
    float* o = attsum + (size_t)v * 8;
    *(float4*)(o) = make_float4(s0, s1, s2, s3);
    *(float4*)(o + 4) = make_float4(s4, (float)(e1 - e0), 0.f, 0.f);
}

// ---------------------------------------------------------------------------
// k_agg<APPLY_BN>: agg[v] = state(v) + (deg+1)*bs + attsum[v]@W_e + sum_e state(src)
// where state(u) = APPLY_BN ? ELU(z16[u]*sc + sh) : h16[u]  (BN folded into the
// gather: saves the k_bn dispatch + 25.6 MB of h16 traffic per layer; ELU is
// deterministic so recomputing per edge is exact).
// Edge loop unroll-8 (8 outstanding 256-B gathers/wave). One wave per node,
// 2 cols/lane. Blocks 0..31 zero the BN-stats replicas for this layer.
// ---------------------------------------------------------------------------
template<int APPLY_BN>
__global__ __launch_bounds__(256) void k_agg(
        const unsigned short* __restrict__ st16, const int* __restrict__ sorted_srcc,
        const float* __restrict__ attsum, const float* __restrict__ scsh,
        const float* __restrict__ W_e_l, const float* __restrict__ bsum_e_l,
        const int* __restrict__ row_start,
        unsigned* __restrict__ agg_hi, unsigned* __restrict__ agg_lo,
        float* __restrict__ stats) {
    int tid = threadIdx.x;
    if (blockIdx.x < NREP) stats[blockIdx.x * 2 * EMB + tid] = 0.f;  // 256 == 2*EMB
    int gid = blockIdx.x * 256 + tid;
    int v = gid >> 6;
    if (v >= NN) return;
    int c = (gid & 63) << 1;
    float2 we0 = *(const float2*)(W_e_l + 0 * EMB + c);
    float2 we1 = *(const float2*)(W_e_l + 1 * EMB + c);
    float2 we2 = *(const float2*)(W_e_l + 2 * EMB + c);
    float2 we3 = *(const float2*)(W_e_l + 3 * EMB + c);
    float2 we4 = *(const float2*)(W_e_l + 4 * EMB + c);
    float2 bs = *(const float2*)(bsum_e_l + c);
    float2 sc2 = make_float2(0.f, 0.f), sh2 = make_float2(0.f, 0.f);
    if (APPLY_BN) {
        sc2 = *(const float2*)(scsh + c);
        sh2 = *(const float2*)(scsh + EMB + c);
    }
    auto state = [&](unsigned u) -> float2 {
        float2 t = uph2(u);
        if (APPLY_BN) {
            t.x = t.x * sc2.x + sh2.x;
            t.y = t.y * sc2.y + sh2.y;
            t.x = (t.x > 0.f) ? t.x : (__expf(t.x) - 1.f);
            t.y = (t.y > 0.f) ? t.y : (__expf(t.y) - 1.f);
        }
        return t;
    };
    float2 hv = state(*(const unsigned*)(st16 + (size_t)v * EMB + c));
    const float* at = attsum + (size_t)v * 8;
    float4 a03 = *(const float4*)(at);
    float2 a45 = *(const float2*)(at + 4);   // a4, deg
    float ax = hv.x + (a45.y + 1.f) * bs.x
             + a03.x*we0.x + a03.y*we1.x + a03.z*we2.x + a03.w*we3.x + a45.x*we4.x;
    float ay = hv.y + (a45.y + 1.f) * bs.y
             + a03.x*we0.y + a03.y*we1.y + a03.z*we2.y + a03.w*we3.y + a45.x*we4.y;
    int e0 = row_start[v], e1 = row_start[v + 1];
    int e = e0;
    for (; e + 8 <= e1; e += 8) {
        int s0 = __builtin_amdgcn_readfirstlane(sorted_srcc[e + 0]);
        int s1 = __builtin_amdgcn_readfirstlane(sorted_srcc[e + 1]);
        int s2 = __builtin_amdgcn_readfirstlane(sorted_srcc[e + 2]);
        int s3 = __builtin_amdgcn_readfirstlane(sorted_srcc[e + 3]);
        int s4 = __builtin_amdgcn_readfirstlane(sorted_srcc[e + 4]);
        int s5 = __builtin_amdgcn_readfirstlane(sorted_srcc[e + 5]);
        int s6 = __builtin_amdgcn_readfirstlane(sorted_srcc[e + 6]);
        int s7 = __builtin_amdgcn_readfirstlane(sorted_srcc[e + 7]);
        unsigned u0 = *(const unsigned*)(st16 + (size_t)s0 * EMB + c);
        unsigned u1 = *(const unsigned*)(st16 + (size_t)s1 * EMB + c);
        unsigned u2 = *(const unsigned*)(st16 + (size_t)s2 * EMB + c);
        unsigned u3 = *(const unsigned*)(st16 + (size_t)s3 * EMB + c);
        unsigned u4 = *(const unsigned*)(st16 + (size_t)s4 * EMB + c);
        unsigned u5 = *(const unsigned*)(st16 + (size_t)s5 * EMB + c);
        unsigned u6 = *(const unsigned*)(st16 + (size_t)s6 * EMB + c);
        unsigned u7 = *(const unsigned*)(st16 + (size_t)s7 * EMB + c);
        float2 h0 = state(u0), h1 = state(u1), h2 = state(u2), h3 = state(u3);
        float2 h4 = state(u4), h5 = state(u5), h6 = state(u6), h7 = state(u7);
        ax += ((h0.x + h1.x) + (h2.x + h3.x)) + ((h4.x + h5.x) + (h6.x + h7.x));
        ay += ((h0.y + h1.y) + (h2.y + h3.y)) + ((h4.y + h5.y) + (h6.y + h7.y));
    }
    for (; e < e1; ++e) {
        int s = __builtin_amdgcn_readfirstlane(sorted_srcc[e]);
        float2 hs = state(*(const unsigned*)(st16 + (size_t)s * EMB + c));
        ax += hs.x;
        ay += hs.y;
    }
    unsigned phi, plo;
    split2(ax, ay, phi, plo);
    size_t o = (size_t)v * (EMB / 2) + (c >> 1);
    agg_hi[o] = phi;
    agg_lo[o] = plo;
}

// ---------------------------------------------------------------------------
// k_mlp (MFMA, hi/lo split = fp32-accurate), fragment-packed weights.
// 32-row tile, 4 waves. D-frag: col=lane&15 (node), row=quad*4+reg.
// Writes z as fp16. BN stats -> replicated buffers (blockIdx&31).
// ---------------------------------------------------------------------------
__global__ __launch_bounds__(256) void k_mlp(
        const unsigned short* __restrict__ aggh, const unsigned short* __restrict__ aggl,
        const unsigned short* __restrict__ W1ph, const unsigned short* __restrict__ W1pl,
        const float* __restrict__ b1_l,
        const unsigned short* __restrict__ W2ph, const unsigned short* __restrict__ W2pl,
        const float* __restrict__ b2_l,
        unsigned short* __restrict__ z16, float* __restrict__ stats) {
    __shared__ unsigned short Ahi[32][136];   // 8.5 KB  (+8 pad)
    __shared__ unsigned short Alo[32][136];   // 8.5 KB
    __shared__ unsigned short Hhi[32][264];   // 16.5 KB (+8 pad)
    __shared__ unsigned short Hlo[32][264];   // 16.5 KB
    int tid = threadIdx.x;
    int r0 = blockIdx.x * 32;
    int rep = blockIdx.x & (NREP - 1);
    // stage A hi/lo tiles (zero-pad rows >= NN)
    #pragma unroll
    for (int it = 0; it < 4; ++it) {
        int idx = it * 256 + tid;       // 0..1023
        int plane = idx >> 9;
        int k = idx & 511;
        int row = k >> 4;
        int cb = (k & 15) * 8;
        int grow = r0 + row;
        uint4 val = make_uint4(0u, 0u, 0u, 0u);
        const unsigned short* srcp = plane ? aggl : aggh;
        if (grow < NN) val = *(const uint4*)(srcp + (size_t)grow * EMB + cb);
        if (plane) *(uint4*)(&Alo[row][cb]) = val;
        else       *(uint4*)(&Ahi[row][cb]) = val;
    }
    __syncthreads();
    int wave = tid >> 6, lane = tid & 63;
    int l16 = lane & 15, quad = lane >> 4;
    // ---- phase 1: wave owns hid cols [64*wave, 64*wave+64)
    {
        bf16x8 ahi[2][4], alo[2][4];
        #pragma unroll
        for (int nt = 0; nt < 2; ++nt)
            #pragma unroll
            for (int kk = 0; kk < 4; ++kk) {
                ahi[nt][kk] = *(const bf16x8*)(&Ahi[nt * 16 + l16][kk * 32 + quad * 8]);
                alo[nt][kk] = *(const bf16x8*)(&Alo[nt * 16 + l16][kk * 32 + quad * 8]);
            }
        #pragma unroll
        for (int h2 = 0; h2 < 4; ++h2) {
            bf16x8 whi[4], wlo[4];
            #pragma unroll
            for (int kk = 0; kk < 4; ++kk) {
                size_t off = ((((size_t)(wave * 4 + h2) * 4) + kk) * 64 + lane) * 8;
                whi[kk] = *(const bf16x8*)(W1ph + off);
                wlo[kk] = *(const bf16x8*)(W1pl + off);
            }
            float4 bv = *(const float4*)(b1_l + wave * 64 + h2 * 16 + quad * 4);
            f32x4 bias = {bv.x, bv.y, bv.z, bv.w};
            #pragma unroll
            for (int nt = 0; nt < 2; ++nt) {
                f32x4 acc = bias;
                #pragma unroll
                for (int kk = 0; kk < 4; ++kk)
                    acc = __builtin_amdgcn_mfma_f32_16x16x32_bf16(whi[kk], ahi[nt][kk], acc, 0, 0, 0);
                #pragma unroll
                for (int kk = 0; kk < 4; ++kk)
                    acc = __builtin_amdgcn_mfma_f32_16x16x32_bf16(whi[kk], alo[nt][kk], acc, 0, 0, 0);
                #pragma unroll
                for (int kk = 0; kk < 4; ++kk)
                    acc = __builtin_amdgcn_mfma_f32_16x16x32_bf16(wlo[kk], ahi[nt][kk], acc, 0, 0, 0);
                float v0 = fmaxf(acc[0], 0.f), v1 = fmaxf(acc[1], 0.f);
                float v2 = fmaxf(acc[2], 0.f), v3 = fmaxf(acc[3], 0.f);
                unsigned hiA, loA, hiB, loB;
                split2(v0, v1, hiA, loA);
                split2(v2, v3, hiB, loB);
                int col = wave * 64 + h2 * 16 + quad * 4;
                *(uint2*)(&Hhi[nt * 16 + l16][col]) = make_uint2(hiA, hiB);
                *(uint2*)(&Hlo[nt * 16 + l16][col]) = make_uint2(loA, loB);
            }
        }
    }
    __syncthreads();
    // ---- phase 2: wave owns out cols [32*wave, 32*wave+32)
    float ss[2][4] = {}, sq[2][4] = {};
    #pragma unroll
    for (int o2 = 0; o2 < 2; ++o2) {
        bf16x8 w2h[8], w2l[8];
        #pragma unroll
        for (int kk = 0; kk < 8; ++kk) {
            size_t off = ((((size_t)(wave * 2 + o2) * 8) + kk) * 64 + lane) * 8;
            w2h[kk] = *(const bf16x8*)(W2ph + off);
            w2l[kk] = *(const bf16x8*)(W2pl + off);
        }
        float4 bv = *(const float4*)(b2_l + wave * 32 + o2 * 16 + quad * 4);
        f32x4 bias = {bv.x, bv.y, bv.z, bv.w};
        #pragma unroll
        for (int nt = 0; nt < 2; ++nt) {
            bf16x8 hh[8], hl[8];
            #pragma unroll
            for (int kk = 0; kk < 8; ++kk) {
                hh[kk] = *(const bf16x8*)(&Hhi[nt * 16 + l16][kk * 32 + quad * 8]);
                hl[kk] = *(const bf16x8*)(&Hlo[nt * 16 + l16][kk * 32 + quad * 8]);
            }
            f32x4 acc = bias;
            #pragma unroll
            for (int kk = 0; kk < 8; ++kk)
                acc = __builtin_amdgcn_mfma_f32_16x16x32_bf16(w2h[kk], hh[kk], acc, 0, 0, 0);
            #pragma unroll
            for (int kk = 0; kk < 8; ++kk)
                acc = __builtin_amdgcn_mfma_f32_16x16x32_bf16(w2h[kk], hl[kk], acc, 0, 0, 0);
            #pragma unroll
            for (int kk = 0; kk < 8; ++kk)
                acc = __builtin_amdgcn_mfma_f32_16x16x32_bf16(w2l[kk], hh[kk], acc, 0, 0, 0);
            int node = r0 + nt * 16 + l16;
            if (node < NN) {
                uint2 p = make_uint2(pkh2(acc[0], acc[1]), pkh2(acc[2], acc[3]));
                *(uint2*)(z16 + (size_t)node * EMB + wave * 32 + o2 * 16 + quad * 4) = p;
                #pragma unroll
                for (int r = 0; r < 4; ++r) {
                    ss[o2][r] += acc[r];
                    sq[o2][r] += acc[r] * acc[r];
                }
            }
        }
    }
    #pragma unroll
    for (int o2 = 0; o2 < 2; ++o2)
        #pragma unroll
        for (int r = 0; r < 4; ++r) {
            float s = ss[o2][r], q = sq[o2][r];
            #pragma unroll
            for (int m = 1; m < 16; m <<= 1) {
                s += __shfl_xor(s, m, 64);
                q += __shfl_xor(q, m, 64);
            }
            if (l16 == 0) {
                int oc = wave * 32 + o2 * 16 + quad * 4 + r;
                atomicAdd(&stats[rep * 2 * EMB + oc], s);
                atomicAdd(&stats[rep * 2 * EMB + EMB + oc], q);
            }
        }
}

// ---------------------------------------------------------------------------
// k_bnscale: ONE block reduces the NREP stats replicas -> sc/sh (1 KB).
// (Next layer's k_agg re-zeroes the replicas.)
// ---------------------------------------------------------------------------
__global__ void k_bnscale(const float* __restrict__ stats,
                          const float* __restrict__ gamma_l, const float* __restrict__ beta_l,
                          float* __restrict__ scsh) {
    int tid = threadIdx.x;  // 128 threads
    float s = 0.f, q = 0.f;
    #pragma unroll
    for (int r = 0; r < NREP; ++r) {
        s += stats[r * 2 * EMB + tid];
        q += stats[r * 2 * EMB + EMB + tid];
    }
    float mu = s * (1.f / NN);
    float var = q * (1.f / NN) - mu * mu;
    float sf = gamma_l[tid] * rsqrtf(var + BN_EPS);
    scsh[tid] = sf;
    scsh[EMB + tid] = beta_l[tid] - mu * sf;
}

// ---------------------------------------------------------------------------
// k_bn (final layer only): z16 -> fp32 z*sc + sh into d_out.
// ---------------------------------------------------------------------------
__global__ void k_bn(const unsigned short* __restrict__ z16, const float* __restrict__ scsh,
                     float* __restrict__ fout) {
    __shared__ float sc[EMB], sh[EMB];
    int tid = threadIdx.x;
    if (tid < EMB) {
        sc[tid] = scsh[tid];
        sh[tid] = scsh[EMB + tid];
    }
    __syncthreads();
    int gid = blockIdx.x * blockDim.x + tid;
    if (gid >= NN * EMB / 4) return;
    int c = (gid & 31) << 2;
    uint2 zp = *(const uint2*)(z16 + (size_t)gid * 4);
    float2 z01 = uph2(zp.x), z23 = uph2(zp.y);
    float o0 = z01.x * sc[c + 0] + sh[c + 0];
    float o1 = z01.y * sc[c + 1] + sh[c + 1];
    float o2 = z23.x * sc[c + 2] + sh[c + 2];
    float o3 = z23.y * sc[c + 3] + sh[c + 3];
    *(float4*)(fout + (size_t)gid * 4) = make_float4(o0, o1, o2, o3);
}

// ---------------------------------------------------------------------------
extern "C" void kernel_launch(void* const* d_in, const int* in_sizes, int n_in,
                              void* d_out, int out_size, void* d_ws, size_t ws_size,
                              hipStream_t stream) {
    const float* x         = (const float*)d_in[0];
    const float* edge_attr = (const float*)d_in[1];
    const int*   edge_idx  = (const int*)d_in[2];
    const float* W_x   = (const float*)d_in[3];
    const float* b_x   = (const float*)d_in[4];
    const float* W_e   = (const float*)d_in[5];
    const float* b_e   = (const float*)d_in[6];
    const float* W1    = (const float*)d_in[7];
    const float* b1    = (const float*)d_in[8];
    const float* W2    = (const float*)d_in[9];
    const float* b2    = (const float*)d_in[10];
    const float* gamma = (const float*)d_in[11];
    const float* beta  = (const float*)d_in[12];
    float* fout = (float*)d_out;  // final BN writes fp32 here

    const int* src = edge_idx;
    const int* dst = edge_idx + NE;

    char* p = (char*)d_ws;
    auto alloc = [&](size_t bytes) { char* q = p; p += (bytes + 255) & ~(size_t)255; return q; };
    unsigned short* h16 = (unsigned short*)alloc((size_t)NN * EMB * 2);
    unsigned short* z16 = (unsigned short*)alloc((size_t)NN * EMB * 2);
    unsigned* agg_hi = (unsigned*)alloc((size_t)NN * EMB * 2);
    unsigned* agg_lo = (unsigned*)alloc((size_t)NN * EMB * 2);
    unsigned short* W1ph = (unsigned short*)alloc((size_t)NL * HID * EMB * 2);
    unsigned short* W1pl = (unsigned short*)alloc((size_t)NL * HID * EMB * 2);
    unsigned short* W2ph = (unsigned short*)alloc((size_t)NL * EMB * HID * 2);
    unsigned short* W2pl = (unsigned short*)alloc((size_t)NL * EMB * HID * 2);
    int*   row_start  = (int*)alloc((NN + 1) * sizeof(int));
    int*   counts     = (int*)alloc(NN * sizeof(int));
    int*   cursor     = (int*)alloc(NN * sizeof(int));
    uint4* sorted_pk  = (uint4*)alloc((size_t)NE * sizeof(uint4));
    int*   sorted_srcc= (int*)alloc((size_t)NE * sizeof(int));
    float* attsum     = (float*)alloc((size_t)NN * 8 * sizeof(float));
    int*   bsum       = (int*)alloc(SCAN_B * sizeof(int));
    int*   bpre       = (int*)alloc(SCAN_B * sizeof(int));
    float* stats      = (float*)alloc((size_t)NREP * 2 * EMB * sizeof(float));
    float* scsh       = (float*)alloc(2 * EMB * sizeof(float));
    float* bsum_x     = (float*)alloc(EMB * sizeof(float));
    float* bsum_e     = (float*)alloc(NL * EMB * sizeof(float));

    k_prep<<<256, 256, 0, stream>>>(b_x, b_e, bsum_x, bsum_e, counts, cursor);
    k_prepw<<<(2 * NL * EMB * HID + 255) / 256, 256, 0, stream>>>(W1, W2, W1ph, W1pl, W2ph, W2pl);
    k_init<<<(NN * 32 + 255) / 256, 256, 0, stream>>>(x, W_x, bsum_x, h16);
    k_hist<<<(NE + 255) / 256, 256, 0, stream>>>(dst, counts);
    k_scan1<<<SCAN_B, 256, 0, stream>>>(counts, bsum);
    k_scan2<<<1, 256, 0, stream>>>(bsum, bpre, row_start);
    k_scan3<<<SCAN_B, 256, 0, stream>>>(counts, bpre, row_start);
    k_fill<<<(NE + 255) / 256, 256, 0, stream>>>(src, dst, edge_attr, row_start, cursor,
                                                 sorted_pk);
    k_esum<<<SCAN_B, 256, 0, stream>>>(sorted_pk, row_start, attsum, sorted_srcc);
    const int AGG_GRID = (NN * 64 + 255) / 256;
    for (int l = 0; l < NL; ++l) {
        if (l == 0) {
            k_agg<0><<<AGG_GRID, 256, 0, stream>>>(
                h16, sorted_srcc, attsum, scsh,
                W_e + (size_t)l * EF * EMB, bsum_e + l * EMB, row_start,
                agg_hi, agg_lo, stats);
        } else {
            k_agg<1><<<AGG_GRID, 256, 0, stream>>>(
                z16, sorted_srcc, attsum, scsh,
                W_e + (size_t)l * EF * EMB, bsum_e + l * EMB, row_start,
                agg_hi, agg_lo, stats);
        }
        k_mlp<<<(NN + 31) / 32, 256, 0, stream>>>(
            (const unsigned short*)agg_hi, (const unsigned short*)agg_lo,
            W1ph + (size_t)l * HID * EMB, W1pl + (size_t)l * HID * EMB, b1 + (size_t)l * HID,
            W2ph + (size_t)l * EMB * HID, W2pl + (size_t)l * EMB * HID, b2 + (size_t)l * EMB,
            z16, stats);
        k_bnscale<<<1, 128, 0, stream>>>(stats, gamma + l * EMB, beta + l * EMB, scsh);
    }
    k_bn<<<(NN * EMB / 4 + 255) / 256, 256, 0, stream>>>(z16, scsh, fout);
}